// Round 13
// baseline (56.275 us; speedup 1.0000x reference)
//
#include <hip/hip_runtime.h>

#define HH 2048
#define WW 2048
#define OH 512
#define OW 512
#define NBLK 1536   // 3ch * 16tcc * 32trr ; tile = 32 cols x 16 rows, 2 cols/thread

typedef float v2f __attribute__((ext_vector_type(2)));

__device__ __forceinline__ float rfl(float v) {
    return __int_as_float(__builtin_amdgcn_readfirstlane(__float_as_int(v)));
}

// No LDS, no barriers. Each thread computes 2 adjacent output cols x 16 bands.
// Per row: one 16-float window (4x dwordx4) serves both cols (2 loads/output).
// 16+16 accumulators via row-filter-then-outer-product; VGPR cap 102 so the
// compiler can keep 1-2 rows of loads in flight (L2-hit latency ~200cyc vs
// 224cyc/row of FMA issue).
__global__ __launch_bounds__(256, 5)
void wpt2_kernel(const float* __restrict__ x,
                 const float* __restrict__ dec_lo,
                 const float* __restrict__ dec_hi,
                 float* __restrict__ out) {
    const int tx = threadIdx.x;           // 0..15 -> col pair
    const int ty = threadIdx.y;           // 0..15 -> row

    // bijective XCD swizzle (1536 % 8 == 0); trr innermost for L2/L3 locality
    const int bid = blockIdx.x;
    const int t   = (bid & 7) * (NBLK / 8) + (bid >> 3);
    const int ch  = t >> 9;               // 0..2
    const int tcc = (t & 511) >> 5;       // 0..15
    const int trr = t & 31;               // 0..31

    // ---- composed 10-tap filters (graycode band order), pinned to SGPRs ----
    float lo[4], hi[4];
#pragma unroll
    for (int j = 0; j < 4; ++j) { lo[j] = dec_lo[j]; hi[j] = dec_hi[j]; }
    float F[4][10];
#pragma unroll
    for (int g = 0; g < 4; ++g) {
        const float* f1 = (g >= 2) ? hi : lo;             // level-1: 0,0,1,1
        const float* f2 = (g == 1 || g == 2) ? hi : lo;   // level-2: 0,1,1,0
#pragma unroll
        for (int d = 0; d < 10; ++d) F[g][d] = 0.f;
#pragma unroll
        for (int j2 = 0; j2 < 4; ++j2)
#pragma unroll
            for (int j1 = 0; j1 < 4; ++j1)
                F[g][2 * j2 + j1] = fmaf(f2[j2], f1[j1], F[g][2 * j2 + j1]);
    }
#pragma unroll
    for (int g = 0; g < 4; ++g)
#pragma unroll
        for (int d = 0; d < 10; ++d) F[g][d] = rfl(F[g][d]);

    const float* xc = x + (size_t)ch * HH * WW;
    const int kr = 16 * trr + ty;
    const int tp = 16 * tcc + tx;         // col-pair index 0..255
    const int kc = 2 * tp;

    // 16-float window cols [8tp-8, 8tp+7]; four 16B-aligned chunks.
    // Only tp==0 wraps (chunks stay within a row). Right edge: 8*255+7=2047 ok.
    int c0 = 8 * tp - 8;  if (c0 < 0) c0 += WW;
    int c1 = 8 * tp - 4;  if (c1 < 0) c1 += WW;
    const int c2 = 8 * tp, c3 = 8 * tp + 4;
    const int r0 = 4 * kr - 6;

    float accA[4][4], accB[4][4];         // [gi][gj] for col kc, kc+1
#pragma unroll
    for (int gi = 0; gi < 4; ++gi)
#pragma unroll
        for (int gj = 0; gj < 4; ++gj) { accA[gi][gj] = 0.f; accB[gi][gj] = 0.f; }

#pragma unroll
    for (int u = 0; u < 10; ++u) {
        int r = r0 + u;  if (r < 0) r += HH;          // negative wrap only
        const float* rp = xc + (size_t)r * WW;
        const float4 a = *reinterpret_cast<const float4*>(rp + c0);
        const float4 b = *reinterpret_cast<const float4*>(rp + c1);
        const float4 c = *reinterpret_cast<const float4*>(rp + c2);
        const float4 d = *reinterpret_cast<const float4*>(rp + c3);
        // w[i] = col (8tp-8+i); colA needs w[11-dc], colB needs w[15-dc]
        const float w[16] = {a.x, a.y, a.z, a.w, b.x, b.y, b.z, b.w,
                             c.x, c.y, c.z, c.w, d.x, d.y, d.z, d.w};

        float sA[4], sB[4];
#pragma unroll
        for (int g = 0; g < 4; ++g) { sA[g] = 0.f; sB[g] = 0.f; }
#pragma unroll
        for (int dc = 0; dc < 10; ++dc) {
            const float vA = w[11 - dc];
            const float vB = w[15 - dc];
#pragma unroll
            for (int g = 0; g < 4; ++g) {
                sA[g] = fmaf(F[g][dc], vA, sA[g]);
                sB[g] = fmaf(F[g][dc], vB, sB[g]);
            }
        }
        const int dr = 9 - u;
#pragma unroll
        for (int gi = 0; gi < 4; ++gi) {
            const float fr = F[gi][dr];
#pragma unroll
            for (int gj = 0; gj < 4; ++gj) {
                accA[gi][gj] = fmaf(fr, sA[gj], accA[gi][gj]);
                accB[gi][gj] = fmaf(fr, sB[gj], accB[gi][gj]);
            }
        }
    }

    // ---- 16 bands x 8B nontemporal stores (native ext_vector type) ----
    const size_t plane = (size_t)OH * OW;
    float* op = out + (size_t)(ch * 16) * plane + (size_t)kr * OW + kc;
#pragma unroll
    for (int gi = 0; gi < 4; ++gi) {
#pragma unroll
        for (int gj = 0; gj < 4; ++gj) {
            v2f v;
            v.x = accA[gi][gj];
            v.y = accB[gi][gj];
            __builtin_nontemporal_store(
                v, reinterpret_cast<v2f*>(op + (size_t)(gi * 4 + gj) * plane));
        }
    }
}

extern "C" void kernel_launch(void* const* d_in, const int* in_sizes, int n_in,
                              void* d_out, int out_size, void* d_ws, size_t ws_size,
                              hipStream_t stream) {
    const float* x      = (const float*)d_in[0];
    const float* dec_lo = (const float*)d_in[1];
    const float* dec_hi = (const float*)d_in[2];
    float* out          = (float*)d_out;

    hipLaunchKernelGGL(wpt2_kernel, dim3(NBLK), dim3(16, 16), 0, stream,
                       x, dec_lo, dec_hi, out);
}

// Round 14
// 24.610 us; speedup vs baseline: 2.2866x; 2.2866x over previous
//
#include <hip/hip_runtime.h>

#define HH 2048
#define WW 2048
#define OH 512
#define OW 512
#define TKC 32             // output cols per tile (threads x)
#define TKR 16             // output rows per tile (threads y)
#define ROWS 70            // 4*TKR + 6 halo rows
#define PITCHF 144         // 16-float lead pad + 128; rows = 576 B = 9 exact lines
#define V4PR 36            // PITCHF/4
#define NV4 (ROWS * V4PR)  // 2520 float4 per tile buffer (39.4 KB)
#define NBLK 512           // 2 blocks/CU (78.75 KB LDS/block), all resident
#define TPB 3              // tiles per block; 512*3 = 1536 = 3ch * 32trr * 16tcc

#define BAR()    __builtin_amdgcn_s_barrier()
#define SCHED0() __builtin_amdgcn_sched_barrier(0)
#define WAITV(n) asm volatile("s_waitcnt vmcnt(" #n ")" ::: "memory")

__device__ __forceinline__ float rfl(float v) {
    return __int_as_float(__builtin_amdgcn_readfirstlane(__float_as_int(v)));
}

__global__ __launch_bounds__(512, 4)
void wpt2_kernel(const float* __restrict__ x,
                 const float* __restrict__ dec_lo,
                 const float* __restrict__ dec_hi,
                 float* __restrict__ out) {
    __shared__ float bufA[NV4 * 4];
    __shared__ float bufB[NV4 * 4];

    const int tx  = threadIdx.x;          // 0..31
    const int ty  = threadIdx.y;          // 0..15
    const int tid = ty * TKC + tx;

    // bijective XCD swizzle (512 % 8 == 0): each XCD gets 64 consecutive chunks
    const int bid = blockIdx.x;
    const int swz = (bid & 7) * (NBLK / 8) + (bid >> 3);
    const int tile0 = swz * TPB;   // tileId = (ch*16 + tcc)*32 + trr (trr innermost)

    // ---- composed 10-tap filters (graycode band order), pinned to SGPRs ----
    float lo[4], hi[4];
#pragma unroll
    for (int j = 0; j < 4; ++j) { lo[j] = dec_lo[j]; hi[j] = dec_hi[j]; }
    float F[4][10];
#pragma unroll
    for (int g = 0; g < 4; ++g) {
        const float* f1 = (g >= 2) ? hi : lo;             // level-1: 0,0,1,1
        const float* f2 = (g == 1 || g == 2) ? hi : lo;   // level-2: 0,1,1,0
#pragma unroll
        for (int d = 0; d < 10; ++d) F[g][d] = 0.f;
#pragma unroll
        for (int j2 = 0; j2 < 4; ++j2)
#pragma unroll
            for (int j1 = 0; j1 < 4; ++j1)
                F[g][2 * j2 + j1] = fmaf(f2[j2], f1[j1], F[g][2 * j2 + j1]);
    }
#pragma unroll
    for (int g = 0; g < 4; ++g)
#pragma unroll
        for (int d = 0; d < 10; ++d) F[g][d] = rfl(F[g][d]);

    // ---- async stage one tile (linear LDS, global_load_lds x16B; 5/lane) ----
    // covers cols [128tcc-16, 128tcc+127]: ends exactly at tile edge, no overhang
    auto stage = [&](float* dst, int tileId) {
        const int ch  = tileId >> 9;
        const int rem = tileId & 511;
        const int tcc = rem >> 5;
        const int trr = rem & 31;
        const float* xc = x + (size_t)ch * HH * WW;
        const int r0 = 64 * trr - 6;
        const int c0 = 128 * tcc - 16;
#pragma unroll
        for (int j = 0; j < 5; ++j) {
            const int i = j * 512 + tid;
            if (j < 4 || i < NV4) {
                const int rr = i / V4PR;
                const int vc = i - rr * V4PR;
                int gr = r0 + rr;      if (gr < 0) gr += HH;   // whole-row wrap only
                int gc = c0 + 4 * vc;  if (gc < 0) gc += WW;   // whole-vec4 wrap only
                __builtin_amdgcn_global_load_lds(
                    (const __attribute__((address_space(1))) void*)&xc[(size_t)gr * WW + gc],
                    (__attribute__((address_space(3))) void*)&dst[i * 4],
                    16, 0, 0);
            }
        }
    };

    // ---- compute one tile (exactly 16 nontemporal stores per thread) ----
    auto compute = [&](const float* buf, int tileId) {
        const int ch  = tileId >> 9;
        const int rem = tileId & 511;
        const int tcc = rem >> 5;
        const int trr = rem & 31;

        __builtin_amdgcn_s_setprio(1);
        float t[4][10];
#pragma unroll
        for (int g = 0; g < 4; ++g)
#pragma unroll
            for (int d = 0; d < 10; ++d) t[g][d] = 0.f;

#pragma unroll
        for (int u = 0; u < 10; ++u) {
            const float* rp = &buf[(4 * ty + u) * PITCHF + 4 * tx + 8];
            const float4 a = *reinterpret_cast<const float4*>(rp);
            const float4 b = *reinterpret_cast<const float4*>(rp + 4);
            const float4 c = *reinterpret_cast<const float4*>(rp + 8);
            const float row[12] = {a.x, a.y, a.z, a.w, b.x, b.y, b.z, b.w,
                                   c.x, c.y, c.z, c.w};
            const int dr = 9 - u;
#pragma unroll
            for (int dc = 0; dc < 10; ++dc) {
                const float v = row[11 - dc];
#pragma unroll
                for (int g = 0; g < 4; ++g)
                    t[g][dc] = fmaf(F[g][dr], v, t[g][dc]);
            }
        }

        const int kr = TKR * trr + ty;
        const int kc = TKC * tcc + tx;
        const size_t plane = (size_t)OH * OW;
        float* op = out + (size_t)(ch * 16) * plane + (size_t)kr * OW + kc;
#pragma unroll
        for (int gi = 0; gi < 4; ++gi) {
#pragma unroll
            for (int gj = 0; gj < 4; ++gj) {
                float acc = 0.f;
#pragma unroll
                for (int dc = 0; dc < 10; ++dc)
                    acc = fmaf(F[gj][dc], t[gi][dc], acc);
                __builtin_nontemporal_store(acc, op + (size_t)(gi * 4 + gj) * plane);
            }
        }
        __builtin_amdgcn_s_setprio(0);
    };

    // ---- depth-1 double-buffer, counted vmcnt (never wait on store-acks) ----
    // Per-wave VMEM order: L0 | L1 S0 | L2 S1 | S2
    // Before compute(ti): Li must be drained; newer ops = 16 stores -> vmcnt(16).
    stage(bufA, tile0 + 0);
    WAITV(0);  BAR(); SCHED0();
    stage(bufB, tile0 + 1); compute(bufA, tile0 + 0);
    WAITV(16); BAR(); SCHED0();
    stage(bufA, tile0 + 2); compute(bufB, tile0 + 1);
    WAITV(16); BAR(); SCHED0();
    compute(bufA, tile0 + 2);
}

extern "C" void kernel_launch(void* const* d_in, const int* in_sizes, int n_in,
                              void* d_out, int out_size, void* d_ws, size_t ws_size,
                              hipStream_t stream) {
    const float* x      = (const float*)d_in[0];
    const float* dec_lo = (const float*)d_in[1];
    const float* dec_hi = (const float*)d_in[2];
    float* out          = (float*)d_out;

    hipLaunchKernelGGL(wpt2_kernel, dim3(NBLK), dim3(TKC, TKR), 0, stream,
                       x, dec_lo, dec_hi, out);
}

// Round 15
// 21.567 us; speedup vs baseline: 2.6093x; 1.1411x over previous
//
#include <hip/hip_runtime.h>

#define HH 2048
#define WW 2048
#define OH 512
#define OW 512
#define TKC 32             // output cols per tile (threads x)
#define TKR 16             // output rows per tile (threads y)
#define SROWS 70           // row-filtered rows per tile (4*TKR + 6)
#define SSZ (SROWS * TKC * 4)   // s-buffer: [70][32][4g] = 8960 floats = 35 KB
#define NPAIR (SROWS * TKC)     // 2240 (r,kc) pairs per tile
#define NBLK 512           // 2 blocks/CU (2 x 35 KB LDS), all resident
#define TPB 3              // 512*3 = 1536 = 3ch * 16tcc * 32trr

#define BAR()     __builtin_amdgcn_s_barrier()
#define SCHED0()  __builtin_amdgcn_sched_barrier(0)
#define WAITV(n)  asm volatile("s_waitcnt vmcnt(" #n ")" ::: "memory")
#define WAITLGKM() asm volatile("s_waitcnt lgkmcnt(0)" ::: "memory")

__device__ __forceinline__ float rfl(float v) {
    return __int_as_float(__builtin_amdgcn_readfirstlane(__float_as_int(v)));
}

__global__ __launch_bounds__(512, 4)
void wpt2_kernel(const float* __restrict__ x,
                 const float* __restrict__ dec_lo,
                 const float* __restrict__ dec_hi,
                 float* __restrict__ out) {
    __shared__ float sA[SSZ];
    __shared__ float sB[SSZ];

    const int tx  = threadIdx.x;          // 0..31
    const int ty  = threadIdx.y;          // 0..15
    const int tid = ty * TKC + tx;

    // bijective XCD swizzle (512 % 8 == 0)
    const int bid = blockIdx.x;
    const int swz = (bid & 7) * (NBLK / 8) + (bid >> 3);
    const int tile0 = swz * TPB;   // tileId = (ch*16 + tcc)*32 + trr

    // ---- composed 10-tap filters (graycode band order), pinned to SGPRs ----
    float lo[4], hi[4];
#pragma unroll
    for (int j = 0; j < 4; ++j) { lo[j] = dec_lo[j]; hi[j] = dec_hi[j]; }
    float F[4][10];
#pragma unroll
    for (int g = 0; g < 4; ++g) {
        const float* f1 = (g >= 2) ? hi : lo;             // level-1: 0,0,1,1
        const float* f2 = (g == 1 || g == 2) ? hi : lo;   // level-2: 0,1,1,0
#pragma unroll
        for (int d = 0; d < 10; ++d) F[g][d] = 0.f;
#pragma unroll
        for (int j2 = 0; j2 < 4; ++j2)
#pragma unroll
            for (int j1 = 0; j1 < 4; ++j1)
                F[g][2 * j2 + j1] = fmaf(f2[j2], f1[j1], F[g][2 * j2 + j1]);
    }
#pragma unroll
    for (int g = 0; g < 4; ++g)
#pragma unroll
        for (int d = 0; d < 10; ++d) F[g][d] = rfl(F[g][d]);

    // ---- issue raw-x loads to REGISTERS for this thread's 5 (r,kc) pairs ----
    // pair p = k*512 + tid ; r = p>>5 (input row 0..69), kc = p&31 (out col)
    // window cols [4kc-8, 4kc+3] as three 16B chunks; all chunks in-bounds
    // (right edge: 128*15 + 4*31 + 3 = 2047).
    auto gload = [&](float4 st[5][3], int tileId) {
        const int ch  = tileId >> 9;
        const int rem = tileId & 511;
        const int tcc = rem >> 5;
        const int trr = rem & 31;
        const float* xc = x + (size_t)ch * HH * WW;
#pragma unroll
        for (int k = 0; k < 5; ++k) {
            const int p = k * 512 + tid;
            if (k < 4 || p < NPAIR) {
                const int r  = p >> 5;
                const int kc = p & 31;
                int grow = 64 * trr - 6 + r;  if (grow < 0) grow += HH;
                const float* rp = xc + (size_t)grow * WW;
                const int cb = 128 * tcc + 4 * kc;
                int c0 = cb - 8;  if (c0 < 0) c0 += WW;   // wrap: tcc==0,kc<=1 only
                int c1 = cb - 4;  if (c1 < 0) c1 += WW;
                st[k][0] = *reinterpret_cast<const float4*>(rp + c0);
                st[k][1] = *reinterpret_cast<const float4*>(rp + c1);
                st[k][2] = *reinterpret_cast<const float4*>(rp + cb);
            }
        }
    };

    // ---- row (horizontal) filter once per input row; write s[r][kc][g] ----
    // s[p][g] = sum_dc F[g][dc] * x[r][4kc+3-dc] ; w[i] = col 4kc-8+i
    auto rowfilt = [&](const float4 st[5][3], float* sbuf) {
#pragma unroll
        for (int k = 0; k < 5; ++k) {
            const int p = k * 512 + tid;
            if (k < 4 || p < NPAIR) {
                const float w[12] = {st[k][0].x, st[k][0].y, st[k][0].z, st[k][0].w,
                                     st[k][1].x, st[k][1].y, st[k][1].z, st[k][1].w,
                                     st[k][2].x, st[k][2].y, st[k][2].z, st[k][2].w};
                float s0 = 0.f, s1 = 0.f, s2 = 0.f, s3 = 0.f;
#pragma unroll
                for (int dc = 0; dc < 10; ++dc) {
                    const float v = w[11 - dc];
                    s0 = fmaf(F[0][dc], v, s0);
                    s1 = fmaf(F[1][dc], v, s1);
                    s2 = fmaf(F[2][dc], v, s2);
                    s3 = fmaf(F[3][dc], v, s3);
                }
                float4 sv; sv.x = s0; sv.y = s1; sv.z = s2; sv.w = s3;
                *reinterpret_cast<float4*>(&sbuf[p * 4]) = sv;   // ds_write_b128
            }
        }
    };

    // ---- column (vertical) pass: 10 ds_read_b128 + 160 FMA + 16 stores ----
    // out row kr needs s rows 4ty..4ty+9 (local): dr = 9-u.
    auto colpass = [&](const float* sbuf, int tileId) {
        const int ch  = tileId >> 9;
        const int rem = tileId & 511;
        const int tcc = rem >> 5;
        const int trr = rem & 31;

        __builtin_amdgcn_s_setprio(1);
        float acc[4][4];
#pragma unroll
        for (int gi = 0; gi < 4; ++gi)
#pragma unroll
            for (int gj = 0; gj < 4; ++gj) acc[gi][gj] = 0.f;

#pragma unroll
        for (int u = 0; u < 10; ++u) {
            const float4 sv = *reinterpret_cast<const float4*>(
                &sbuf[((4 * ty + u) * TKC + tx) * 4]);
            const int dr = 9 - u;
#pragma unroll
            for (int gi = 0; gi < 4; ++gi) {
                const float fr = F[gi][dr];
                acc[gi][0] = fmaf(fr, sv.x, acc[gi][0]);
                acc[gi][1] = fmaf(fr, sv.y, acc[gi][1]);
                acc[gi][2] = fmaf(fr, sv.z, acc[gi][2]);
                acc[gi][3] = fmaf(fr, sv.w, acc[gi][3]);
            }
        }

        const int kr = TKR * trr + ty;
        const int kc = TKC * tcc + tx;
        const size_t plane = (size_t)OH * OW;
        float* op = out + (size_t)(ch * 16) * plane + (size_t)kr * OW + kc;
#pragma unroll
        for (int gi = 0; gi < 4; ++gi)
#pragma unroll
            for (int gj = 0; gj < 4; ++gj)
                __builtin_nontemporal_store(acc[gi][gj],
                                            op + (size_t)(gi * 4 + gj) * plane);
        __builtin_amdgcn_s_setprio(0);
    };

    // ---- pipeline: loads(i+1) issued before colpass(i); rowfilt after drain ----
    float4 st[5][3];

    gload(st, tile0 + 0);
    WAITV(0);
    rowfilt(st, sA);
    WAITLGKM(); BAR(); SCHED0();

    gload(st, tile0 + 1); SCHED0();      // pin loads before colpass
    colpass(sA, tile0 + 0);
    WAITV(16);                           // drain 15 loads; 16 newer stores excluded
    rowfilt(st, sB);
    WAITLGKM(); BAR(); SCHED0();

    gload(st, tile0 + 2); SCHED0();
    colpass(sB, tile0 + 1);
    WAITV(16);
    rowfilt(st, sA);
    WAITLGKM(); BAR(); SCHED0();

    colpass(sA, tile0 + 2);
}

extern "C" void kernel_launch(void* const* d_in, const int* in_sizes, int n_in,
                              void* d_out, int out_size, void* d_ws, size_t ws_size,
                              hipStream_t stream) {
    const float* x      = (const float*)d_in[0];
    const float* dec_lo = (const float*)d_in[1];
    const float* dec_hi = (const float*)d_in[2];
    float* out          = (float*)d_out;

    hipLaunchKernelGGL(wpt2_kernel, dim3(NBLK), dim3(TKC, TKR), 0, stream,
                       x, dec_lo, dec_hi, out);
}